// Round 1
// baseline (75.601 us; speedup 1.0000x reference)
//
#include <hip/hip_runtime.h>

// Problem constants (match reference)
#define LSEQ 2048   // sequence length
#define NS   1022   // number of distances s = 2..1023
#define NF   5110   // NS * 5 output features
#define NB   8      // batch
#define IT   128    // i-positions per block
#define TPB  256    // threads per block

__device__ __forceinline__ float4 zero4() { return make_float4(0.f, 0.f, 0.f, 0.f); }

// base pairing score: 2*y0*z3 + 3*y1*z2 + 3*y2*z1 + 2*y3*z0
__device__ __forceinline__ float basescore(const float4 y, const float4 z) {
    return 2.f * y.x * z.w + 3.f * y.y * z.z + 3.f * y.z * z.y + 2.f * y.w * z.x;
}

__global__ __launch_bounds__(TPB) void fdcnn_kernel(const float4* __restrict__ x,
                                                    float* __restrict__ out) {
    __shared__ float4 xs[LSEQ];   // 32 KB: whole x[n] row
    const int n = blockIdx.z;
    const float4* xg = x + (size_t)n * LSEQ;
    #pragma unroll
    for (int k = 0; k < LSEQ / TPB; ++k)
        xs[threadIdx.x + k * TPB] = xg[threadIdx.x + k * TPB];
    __syncthreads();

    const int sidx = blockIdx.x * TPB + threadIdx.x;  // 0..NS-1
    if (sidx >= NS) return;
    const int s = sidx + 2;                           // distance 2..1023
    const int i0 = blockIdx.y * IT;

    float* op = out + ((size_t)n * LSEQ + i0) * (size_t)NF + (size_t)sidx * 5;

    // Rolling registers:
    //   at iteration i we need y1=xs[i+s+1], y2=xs[i+s+2], y3=xs[i+s+3]
    //                          z1=xs[i-s-1], z2=xs[i-s-2], z3=xs[i-s-3]
    //   per-iter new loads: y3 (pos i+s+3) and z1 (pos i-s-1); rest roll.
    float4 yA, yB, zA, zB;  // yA=y1, yB=y2 (pre-shift); zA=z3, zB=z2
    {
        int p = i0 + s + 1;
        yA = xs[p & (LSEQ - 1)]; if (p >= LSEQ) yA = zero4();
        p = i0 + s + 2;
        yB = xs[p & (LSEQ - 1)]; if (p >= LSEQ) yB = zero4();
        int q = i0 - s - 3;
        zA = xs[q & (LSEQ - 1)]; if (q < 0) zA = zero4();
        q = i0 - s - 2;
        zB = xs[q & (LSEQ - 1)]; if (q < 0) zB = zero4();
    }

    #pragma unroll 8
    for (int ii = 0; ii < IT; ++ii) {
        const int i = i0 + ii;

        int p = i + s + 3;
        float4 yC = xs[p & (LSEQ - 1)]; if (p >= LSEQ) yC = zero4();
        int q = i - s - 1;
        float4 zC = xs[q & (LSEQ - 1)]; if (q < 0) zC = zero4();

        const float4 y1 = yA, y2 = yB, y3 = yC;
        const float4 z3 = zA, z2 = zB, z1 = zC;

        // j=0: main (f=s+1,b=s+1) with GU wobble
        float o0 = basescore(y1, z1) + 2.f * (y1.z * z1.w + y1.w * z1.z);
        // j=1: left bulge d=1 (f=s+1,b=s+2)
        float o1 = basescore(y1, z2);
        // j=2: left bulge d=2 (f=s+1,b=s+3)
        float o2 = basescore(y1, z3);
        // j=3: right bulge d=1 (f=s+2,b=s+1)
        float o3 = basescore(y2, z1);
        // j=4: right bulge d=2 (f=s+3,b=s+1)
        float o4 = basescore(y3, z1);

        op[0] = o0; op[1] = o1; op[2] = o2; op[3] = o3; op[4] = o4;
        op += NF;

        yA = yB; yB = yC;   // roll (copy-propagated away after unroll)
        zA = zB; zB = zC;
    }
}

extern "C" void kernel_launch(void* const* d_in, const int* in_sizes, int n_in,
                              void* d_out, int out_size, void* d_ws, size_t ws_size,
                              hipStream_t stream) {
    const float4* x = (const float4*)d_in[0];
    float* out = (float*)d_out;
    dim3 grid((NS + TPB - 1) / TPB, LSEQ / IT, NB);  // (4, 16, 8)
    dim3 block(TPB);
    fdcnn_kernel<<<grid, block, 0, stream>>>(x, out);
}

// Round 2
// 72.813 us; speedup vs baseline: 1.0383x; 1.0383x over previous
//
#include <hip/hip_runtime.h>

// Problem constants (match reference)
#define LSEQ 2048   // sequence length
#define NS   1022   // number of distances s = 2..1023
#define NF   5110   // NS * 5 output features
#define NB   8      // batch
#define IT   128    // i-positions per block
#define GI   4      // i-positions per store group (stage granularity)
#define TPB  256    // threads per block
#define FPB  (TPB * 5)  // 1280 contiguous features covered by one block

__device__ __forceinline__ float4 zero4() { return make_float4(0.f, 0.f, 0.f, 0.f); }

// base pairing score: 2*y0*z3 + 3*y1*z2 + 3*y2*z1 + 2*y3*z0
__device__ __forceinline__ float basescore(const float4 y, const float4 z) {
    return 2.f * y.x * z.w + 3.f * y.y * z.z + 3.f * y.z * z.y + 2.f * y.w * z.x;
}

__global__ __launch_bounds__(TPB) void fdcnn_kernel(const float4* __restrict__ x,
                                                    float* __restrict__ out) {
    __shared__ float4 xs[LSEQ];       // 32 KB: whole x[n] row
    __shared__ float st[GI][FPB];     // 20 KB: staged outputs for GI i-positions

    const int t = threadIdx.x;
    const int n = blockIdx.z;
    const float4* xg = x + (size_t)n * LSEQ;
    #pragma unroll
    for (int k = 0; k < LSEQ / TPB; ++k)
        xs[t + k * TPB] = xg[t + k * TPB];
    __syncthreads();

    const int sidx = blockIdx.x * TPB + t;   // 0..1023 (>=NS lanes compute garbage, clipped at store)
    const int s = sidx + 2;
    const int i0 = blockIdx.y * IT;
    const int fbase = blockIdx.x * FPB;      // first feature this block covers

    // Rolling registers:
    //   at iteration i we need y1=xs[i+s+1], y2=xs[i+s+2], y3=xs[i+s+3]
    //                          z1=xs[i-s-1], z2=xs[i-s-2], z3=xs[i-s-3]
    //   per-iter new loads: y3 (pos i+s+3) and z1 (pos i-s-1); rest roll.
    float4 yA, yB, zA, zB;  // yA=y1, yB=y2 (pre-shift); zA=z3, zB=z2
    {
        int p = i0 + s + 1;
        yA = xs[p & (LSEQ - 1)]; if (p >= LSEQ) yA = zero4();
        p = i0 + s + 2;
        yB = xs[p & (LSEQ - 1)]; if (p >= LSEQ) yB = zero4();
        int q = i0 - s - 3;
        zA = xs[q & (LSEQ - 1)]; if (q < 0) zA = zero4();
        q = i0 - s - 2;
        zB = xs[q & (LSEQ - 1)]; if (q < 0) zB = zero4();
    }

    for (int gb = 0; gb < IT / GI; ++gb) {
        // ---- compute phase: GI positions, stage 5 floats each into LDS ----
        #pragma unroll
        for (int ig = 0; ig < GI; ++ig) {
            const int i = i0 + gb * GI + ig;

            int p = i + s + 3;
            float4 yC = xs[p & (LSEQ - 1)]; if (p >= LSEQ) yC = zero4();
            int q = i - s - 1;
            float4 zC = xs[q & (LSEQ - 1)]; if (q < 0) zC = zero4();

            const float4 y1 = yA, y2 = yB, y3 = yC;
            const float4 z3 = zA, z2 = zB, z1 = zC;

            float* sp = &st[ig][t * 5];
            // j=0: main (f=s+1,b=s+1) with GU wobble
            sp[0] = basescore(y1, z1) + 2.f * (y1.z * z1.w + y1.w * z1.z);
            sp[1] = basescore(y1, z2);   // left bulge d=1
            sp[2] = basescore(y1, z3);   // left bulge d=2
            sp[3] = basescore(y2, z1);   // right bulge d=1
            sp[4] = basescore(y3, z1);   // right bulge d=2

            yA = yB; yB = yC;
            zA = zB; zB = zC;
        }
        __syncthreads();

        // ---- store phase: 5 coalesced float4 per thread ----
        const size_t obase = ((size_t)n * LSEQ + (i0 + gb * GI)) * (size_t)NF;
        #pragma unroll
        for (int k = 0; k < 5; ++k) {
            const int v  = k * TPB + t;       // 0..1279: flat float4 index in stage
            const int ig = v / 320;           // which i within group (320 float4 per i)
            const int fo = (v - ig * 320) * 4; // float offset within the block's features
            const int rem = NF - (fbase + fo);
            const float4 val = *(const float4*)&st[ig][fo];
            float* dst = out + obase + (size_t)ig * NF + fbase + fo;
            if (rem >= 4) {
                *(float4*)dst = val;
            } else if (rem > 0) {             // feature-tail of the last block (rem==2)
                dst[0] = val.x;
                if (rem > 1) dst[1] = val.y;
            }
        }
        __syncthreads();
    }
}

extern "C" void kernel_launch(void* const* d_in, const int* in_sizes, int n_in,
                              void* d_out, int out_size, void* d_ws, size_t ws_size,
                              hipStream_t stream) {
    const float4* x = (const float4*)d_in[0];
    float* out = (float*)d_out;
    dim3 grid((NS + TPB - 1) / TPB, LSEQ / IT, NB);  // (4, 16, 8)
    dim3 block(TPB);
    fdcnn_kernel<<<grid, block, 0, stream>>>(x, out);
}